// Round 8
// baseline (408.027 us; speedup 1.0000x reference)
//
#include <hip/hip_runtime.h>

#define TOK 2048
#define DIM 1024
#define HID 4096
#define NE 8
#define KSPLIT 4
#define TMAX 24
#define NCAST 2048

typedef unsigned short u16;
typedef __attribute__((ext_vector_type(8))) short s16x8;
typedef __attribute__((ext_vector_type(4))) float f32x4;

__device__ __forceinline__ u16 f2b(float f) {
  unsigned u = __builtin_bit_cast(unsigned, f);
  unsigned r = (u + 0x7fffu + ((u >> 16) & 1u)) >> 16;
  return (u16)r;
}

__device__ __forceinline__ void gld_lds16(const void* g, void* l) {
  __builtin_amdgcn_global_load_lds((const __attribute__((address_space(1))) void*)g,
                                   (__attribute__((address_space(3))) void*)l, 16, 0, 0);
}

// ---------------- gating (blocks 0..511) + w1/w2/wp bf16 cast (blocks 512..512+NCAST) ----------------
__global__ __launch_bounds__(256) void k_gate(const float* __restrict__ x,
    const float* __restrict__ noise, const float* __restrict__ gw,
    const float* __restrict__ nw, const float* __restrict__ w1,
    const float* __restrict__ w2, const float* __restrict__ wp,
    u16* __restrict__ w1b, u16* __restrict__ w2b, u16* __restrict__ wpb,
    int* __restrict__ tok_e, float* __restrict__ tok_w,
    int* __restrict__ bhist, float* __restrict__ bgw, u16* __restrict__ x16) {
  if (blockIdx.x >= TOK / 4) {
    // MLP-friendly cast: 6 sweeps x (8 independent float4 loads -> 32 cvt -> 4 stores)
    const int cb = blockIdx.x - TOK / 4;              // 0..NCAST-1
    const size_t NPT = (size_t)NE * HID * DIM;        // 33554432
    const size_t SW = (size_t)NCAST * 256 * 32;       // 16777216 floats/sweep (2 sweeps/tensor)
    const size_t base = ((size_t)cb * 256 + threadIdx.x) * 32;
#pragma unroll
    for (int s = 0; s < 6; ++s) {
      const float* in = (s < 2) ? w1 : (s < 4) ? w2 : wp;
      u16* o = (s < 2) ? w1b : (s < 4) ? w2b : wpb;
      const size_t j = (size_t)(s & 1) * SW + base;
      f32x4 f[8];
#pragma unroll
      for (int q = 0; q < 8; ++q) f[q] = *(const f32x4*)(in + j + q * 4);
      u16 u[32];
#pragma unroll
      for (int q = 0; q < 8; ++q) {
        u[q * 4 + 0] = f2b(f[q][0]); u[q * 4 + 1] = f2b(f[q][1]);
        u[q * 4 + 2] = f2b(f[q][2]); u[q * 4 + 3] = f2b(f[q][3]);
      }
#pragma unroll
      for (int q = 0; q < 4; ++q) *(s16x8*)(o + j + q * 8) = *(const s16x8*)(u + q * 8);
    }
    return;
  }
  const int wid = threadIdx.x >> 6, lane = threadIdx.x & 63;
  const int t = blockIdx.x * 4 + wid;
  const float* xr = x + (size_t)t * DIM + lane * 16;
  float acc[NE];
#pragma unroll
  for (int e = 0; e < NE; ++e) acc[e] = 0.f;
  u16 xb[16];
#pragma unroll
  for (int j = 0; j < 4; ++j) {
    float4 xv = *(const float4*)(xr + j * 4);
    xb[j * 4 + 0] = f2b(xv.x); xb[j * 4 + 1] = f2b(xv.y);
    xb[j * 4 + 2] = f2b(xv.z); xb[j * 4 + 3] = f2b(xv.w);
#pragma unroll
    for (int e = 0; e < NE; ++e) {
      float4 gv = *(const float4*)(gw + e * DIM + lane * 16 + j * 4);
      acc[e] += xv.x * gv.x + xv.y * gv.y + xv.z * gv.z + xv.w * gv.w;
    }
  }
  *(s16x8*)(x16 + (size_t)t * DIM + lane * 16) = *(const s16x8*)xb;
  *(s16x8*)(x16 + (size_t)t * DIM + lane * 16 + 8) = *(const s16x8*)(xb + 8);
#pragma unroll
  for (int e = 0; e < NE; ++e) {
#pragma unroll
    for (int off = 32; off >= 1; off >>= 1) acc[e] += __shfl_xor(acc[e], off);
  }
  float m = acc[0];
#pragma unroll
  for (int e = 1; e < NE; ++e) m = fmaxf(m, acc[e]);
  float p[NE]; float s = 0.f;
#pragma unroll
  for (int e = 0; e < NE; ++e) { p[e] = expf(acc[e] - m); s += p[e]; }
  float inv = 1.f / s;
  float v[NE];
#pragma unroll
  for (int e = 0; e < NE; ++e) v[e] = acc[e] + noise[t * NE + e] * nw[e];
  float v0 = -3.4e38f, v1 = -3.4e38f; int i0 = 0, i1 = 0;
#pragma unroll
  for (int e = 0; e < NE; ++e) {
    float ve = v[e];
    if (ve > v0) { v1 = v0; i1 = i0; v0 = ve; i0 = e; }
    else if (ve > v1) { v1 = ve; i1 = e; }
  }
  float e1 = expf(v1 - v0);
  float den = 1.f + e1;
  float w0 = 1.f / den, w1v = e1 / den;

  __shared__ float pl[4][NE];
  __shared__ int el[4][2];
  if (lane == 0) {
#pragma unroll
    for (int e = 0; e < NE; ++e) pl[wid][e] = p[e] * inv;
    el[wid][0] = i0; el[wid][1] = i1;
    tok_e[t * 2] = i0; tok_e[t * 2 + 1] = i1;
    tok_w[t * 2] = w0; tok_w[t * 2 + 1] = w1v;
  }
  __syncthreads();
  if (threadIdx.x < NE) {
    const int e = threadIdx.x;
    float ps = pl[0][e] + pl[1][e] + pl[2][e] + pl[3][e];
    int h = 0;
#pragma unroll
    for (int j = 0; j < 4; ++j) {
      h += (el[j][0] == e);
      h += (el[j][1] == e);
    }
    bgw[blockIdx.x * NE + e] = ps;
    bhist[blockIdx.x * NE + e] = h;
  }
}

// ---------------- scan: offsets, counts, prefix, 256-row tile table, lb loss ----------------
__global__ __launch_bounds__(512) void k_scan(const int* __restrict__ bhist,
    const float* __restrict__ bgw, int* __restrict__ blk_off, int* __restrict__ prefix,
    int* __restrict__ counts, int* __restrict__ tile_tab, float* __restrict__ loss_out) {
  const int i = threadIdx.x, lane = i & 63, wv = i >> 6;
  __shared__ int wsum[8];
  __shared__ float wfs[8];
  __shared__ int etot[8];
  __shared__ float fsum[8];
  for (int e = 0; e < NE; ++e) {
    int v = bhist[i * NE + e];
    int sc = v;
#pragma unroll
    for (int off = 1; off < 64; off <<= 1) {
      int u = __shfl_up(sc, off);
      if (lane >= off) sc += u;
    }
    float f = bgw[i * NE + e];
#pragma unroll
    for (int off = 32; off >= 1; off >>= 1) f += __shfl_xor(f, off);
    if (lane == 63) wsum[wv] = sc;
    if (lane == 0) wfs[wv] = f;
    __syncthreads();
    int base = 0;
    for (int w2 = 0; w2 < wv; ++w2) base += wsum[w2];
    blk_off[i * NE + e] = base + sc - v;
    if (i == 0) {
      float tf = 0.f;
      for (int w2 = 0; w2 < 8; ++w2) tf += wfs[w2];
      fsum[e] = tf;
    }
    if (i == 511) etot[e] = base + sc;
    __syncthreads();
  }
  if (i == 0) {
    int sacc = 0;
    float l = 0.f;
    int tt = 0;
#pragma unroll
    for (int e = 0; e < NE; ++e) { prefix[e] = sacc; counts[e] = etot[e]; sacc += etot[e]; }
    for (int e = 0; e < NE; ++e) {
      const int nmt = (etot[e] + 255) >> 8;
      for (int m2 = 0; m2 < nmt; ++m2) tile_tab[tt++] = (e << 16) | m2;
    }
    for (; tt < TMAX; ++tt) tile_tab[tt] = -1;
#pragma unroll
    for (int e = 0; e < NE; ++e) {
      float d = fsum[e] * (1.f / TOK) - 0.125f;
      l += d * d;
    }
    *loss_out = l * (0.01f / NE);
  }
}

// ---------------- build compacted expert lists + inverse map ----------------
__global__ __launch_bounds__(256) void k_build(const int* __restrict__ tok_e,
    const float* __restrict__ tok_w, const int* __restrict__ prefix,
    const int* __restrict__ blk_off, int* __restrict__ ent, float* __restrict__ entw,
    int* __restrict__ inv) {
  const int t = blockIdx.x * 256 + threadIdx.x;
  const int g = t >> 2;
  const int base = (t & 3) * 2;
  int ee[8];
#pragma unroll
  for (int j = 0; j < 8; ++j) ee[j] = tok_e[g * 8 + j];
#pragma unroll
  for (int s = 0; s < 2; ++s) {
    const int e = ee[base + s];
    int rank = 0;
#pragma unroll
    for (int j = 0; j < 8; ++j) rank += (j < base + s) && (ee[j] == e);
    const int idx = prefix[e] + blk_off[g * NE + e] + rank;
    ent[idx] = t * 2 + s;
    entw[idx] = tok_w[t * 2 + s];
    inv[t * 2 + s] = idx;
  }
}

// ================= GEMM1: 256x128 tile, 8 waves, counted-vmcnt depth-2 pipeline =================
__global__ __launch_bounds__(512) void k_gemm1f(const u16* __restrict__ x16,
    const u16* __restrict__ w1b, const u16* __restrict__ w2b,
    const float* __restrict__ b1, const float* __restrict__ b2,
    const int* __restrict__ ent, const int* __restrict__ counts,
    const int* __restrict__ prefix, const int* __restrict__ tile_tab,
    u16* __restrict__ act) {
  const int tt = tile_tab[blockIdx.y];
  if (tt < 0) return;
  const int e = tt >> 16, mt = tt & 0xffff, nt = blockIdx.x;
  const int cnt = counts[e];
  const int pfx = prefix[e];
  const int tid = threadIdx.x, w = tid >> 6, l = tid & 63;

  __shared__ u16 smem[2][16384];   // A: [0,8192) 256x32, B1: [8192,12288), B2: [12288,16384)

  const int r0 = tid >> 2;
  const int c = (tid & 3) ^ ((tid >> 3) & 3);
  int g0 = mt * 256 + r0;       if (g0 >= cnt) g0 = cnt - 1;
  int g1 = mt * 256 + 128 + r0; if (g1 >= cnt) g1 = cnt - 1;
  const u16* sa0 = x16 + (size_t)(ent[pfx + g0] >> 1) * DIM + c * 8;
  const u16* sa1 = x16 + (size_t)(ent[pfx + g1] >> 1) * DIM + c * 8;
  const u16* sb1 = w1b + ((size_t)e * HID + nt * 128 + r0) * DIM + c * 8;
  const u16* sb2 = w2b + ((size_t)e * HID + nt * 128 + r0) * DIM + c * 8;
  const int oA0 = tid * 8, oA1 = 4096 + tid * 8;
  const int oB1 = 8192 + tid * 8, oB2 = 12288 + tid * 8;

  const int wr = w >> 1, wc = w & 1;
  const int xs = ((l >> 4) ^ ((l >> 1) & 3)) * 8;
  const int ra = (wr * 64 + (l & 15)) * 32 + xs;
  const int rb = (wc * 64 + (l & 15)) * 32 + xs;

  f32x4 acc1[4][4], acc2[4][4];
#pragma unroll
  for (int m = 0; m < 4; ++m)
#pragma unroll
    for (int n = 0; n < 4; ++n) {
      acc1[m][n] = (f32x4){0.f, 0.f, 0.f, 0.f};
      acc2[m][n] = (f32x4){0.f, 0.f, 0.f, 0.f};
    }

  auto STAGE = [&](int buf, int k0) {
    gld_lds16(sa0 + k0, &smem[buf][oA0]);
    gld_lds16(sa1 + k0, &smem[buf][oA1]);
    gld_lds16(sb1 + k0, &smem[buf][oB1]);
    gld_lds16(sb2 + k0, &smem[buf][oB2]);
  };

  const int NT = DIM / 32;
  STAGE(0, 0);
  STAGE(1, 32);
  asm volatile("s_waitcnt vmcnt(4)" ::: "memory");
  __builtin_amdgcn_s_barrier();
  __builtin_amdgcn_sched_barrier(0);
  int cur = 0;
  for (int kt = 0; kt < NT; ++kt) {
    const u16* S = &smem[cur][0];
    s16x8 af[4];
#pragma unroll
    for (int m = 0; m < 4; ++m) af[m] = *(const s16x8*)(S + ra + m * 512);
#pragma unroll
    for (int n = 0; n < 4; ++n) {
      s16x8 bf1 = *(const s16x8*)(S + 8192 + rb + n * 512);
      s16x8 bf2 = *(const s16x8*)(S + 12288 + rb + n * 512);
#pragma unroll
      for (int m = 0; m < 4; ++m) {
        acc1[m][n] = __builtin_amdgcn_mfma_f32_16x16x32_bf16(af[m], bf1, acc1[m][n], 0, 0, 0);
        acc2[m][n] = __builtin_amdgcn_mfma_f32_16x16x32_bf16(af[m], bf2, acc2[m][n], 0, 0, 0);
      }
    }
    if (kt + 1 < NT) {
      asm volatile("s_waitcnt lgkmcnt(0)" ::: "memory");
      __builtin_amdgcn_sched_barrier(0);
      __builtin_amdgcn_s_barrier();            // all waves done reading smem[cur]
      if (kt + 2 < NT) {
        STAGE(cur, (kt + 2) * 32);             // overwrite with tile kt+2
        asm volatile("s_waitcnt vmcnt(4)" ::: "memory");   // tile kt+1 arrived
      } else {
        asm volatile("s_waitcnt vmcnt(0)" ::: "memory");
      }
      __builtin_amdgcn_s_barrier();            // all waves see tile kt+1
      __builtin_amdgcn_sched_barrier(0);
    }
    cur ^= 1;
  }

#pragma unroll
  for (int n = 0; n < 4; ++n) {
    const int col = nt * 128 + wc * 64 + n * 16 + (l & 15);
    const float bb1 = b1[(size_t)e * HID + col];
    const float bb2 = b2[(size_t)e * HID + col];
#pragma unroll
    for (int m = 0; m < 4; ++m) {
#pragma unroll
      for (int r = 0; r < 4; ++r) {
        const int row = mt * 256 + wr * 64 + m * 16 + (l >> 4) * 4 + r;
        if (row < cnt) {
          float h = acc1[m][n][r] + bb1;
          float g = acc2[m][n][r] + bb2;
          float a = h * g / (1.f + expf(-g));
          act[(size_t)(pfx + row) * HID + col] = f2b(a);
        }
      }
    }
  }
}

// ================= GEMM2: 256x256 tile, 8 waves, split-K=4, counted-vmcnt pipeline =================
__global__ __launch_bounds__(512) void k_gemm2f(const u16* __restrict__ act,
    const u16* __restrict__ wpb, const float* __restrict__ bp,
    const float* __restrict__ entw, const int* __restrict__ counts,
    const int* __restrict__ prefix, const int* __restrict__ tile_tab,
    float* __restrict__ yp) {
  const int tt = tile_tab[blockIdx.y];
  if (tt < 0) return;
  const int e = tt >> 16, mt = tt & 0xffff;
  const int sk = blockIdx.z, nt = blockIdx.x;
  const int cnt = counts[e];
  const int pfx = prefix[e];
  const int tid = threadIdx.x, w = tid >> 6, l = tid & 63;

  __shared__ u16 smem[2][16384];

  const int r0 = tid >> 2;
  const int c = (tid & 3) ^ ((tid >> 3) & 3);
  int g0 = mt * 256 + r0;       if (g0 >= cnt) g0 = cnt - 1;
  int g1 = mt * 256 + 128 + r0; if (g1 >= cnt) g1 = cnt - 1;
  const int kbase = sk * (HID / KSPLIT);
  const u16* sa0 = act + (size_t)(pfx + g0) * HID + kbase + c * 8;
  const u16* sa1 = act + (size_t)(pfx + g1) * HID + kbase + c * 8;
  const u16* sb0 = wpb + ((size_t)e * DIM + nt * 256 + r0) * HID + kbase + c * 8;
  const u16* sb1 = sb0 + (size_t)128 * HID;
  const int oA0 = tid * 8, oA1 = 4096 + tid * 8;
  const int oB0 = 8192 + tid * 8, oB1 = 12288 + tid * 8;

  const int wr = w >> 2, wc = w & 3;
  const int xs = ((l >> 4) ^ ((l >> 1) & 3)) * 8;
  const int ra = (wr * 128 + (l & 15)) * 32 + xs;
  const int rb = 8192 + (wc * 64 + (l & 15)) * 32 + xs;

  f32x4 acc[8][4];
#pragma unroll
  for (int m = 0; m < 8; ++m)
#pragma unroll
    for (int n = 0; n < 4; ++n) acc[m][n] = (f32x4){0.f, 0.f, 0.f, 0.f};

  auto STAGE = [&](int buf, int k0) {
    gld_lds16(sa0 + k0, &smem[buf][oA0]);
    gld_lds16(sa1 + k0, &smem[buf][oA1]);
    gld_lds16(sb0 + k0, &smem[buf][oB0]);
    gld_lds16(sb1 + k0, &smem[buf][oB1]);
  };

  const int NIT = HID / KSPLIT / 32;
  STAGE(0, 0);
  STAGE(1, 32);
  asm volatile("s_waitcnt vmcnt(4)" ::: "memory");
  __builtin_amdgcn_s_barrier();
  __builtin_amdgcn_sched_barrier(0);
  int cur = 0;
  for (int kt = 0; kt < NIT; ++kt) {
    const u16* S = &smem[cur][0];
#pragma unroll
    for (int n = 0; n < 4; ++n) {
      s16x8 bf = *(const s16x8*)(S + rb + n * 512);
#pragma unroll
      for (int m = 0; m < 8; ++m) {
        s16x8 af = *(const s16x8*)(S + ra + m * 512);
        acc[m][n] = __builtin_amdgcn_mfma_f32_16x16x32_bf16(af, bf, acc[m][n], 0, 0, 0);
      }
    }
    if (kt + 1 < NIT) {
      asm volatile("s_waitcnt lgkmcnt(0)" ::: "memory");
      __builtin_amdgcn_sched_barrier(0);
      __builtin_amdgcn_s_barrier();
      if (kt + 2 < NIT) {
        STAGE(cur, (kt + 2) * 32);
        asm volatile("s_waitcnt vmcnt(4)" ::: "memory");
      } else {
        asm volatile("s_waitcnt vmcnt(0)" ::: "memory");
      }
      __builtin_amdgcn_s_barrier();
      __builtin_amdgcn_sched_barrier(0);
    }
    cur ^= 1;
  }

#pragma unroll
  for (int n = 0; n < 4; ++n) {
    const int col = nt * 256 + wc * 64 + n * 16 + (l & 15);
    const float bpv = (sk == 0) ? bp[(size_t)e * DIM + col] : 0.f;
#pragma unroll
    for (int m = 0; m < 8; ++m) {
#pragma unroll
      for (int r = 0; r < 4; ++r) {
        const int row = mt * 256 + wr * 128 + m * 16 + (l >> 4) * 4 + r;
        if (row < cnt) {
          const int idx = pfx + row;
          yp[((size_t)sk * (TOK * 2) + idx) * DIM + col] = entw[idx] * (acc[m][n][r] + bpv);
        }
      }
    }
  }
}

// ---------------- final: out[t] = sum over 2 slots x KSPLIT partials ----------------
__global__ __launch_bounds__(256) void k_final(const float* __restrict__ yp,
    const int* __restrict__ inv, float* __restrict__ out) {
  const int t = blockIdx.x;
  const int d = threadIdx.x * 4;
  const int i0 = inv[t * 2], i1 = inv[t * 2 + 1];
  float4 s = {0.f, 0.f, 0.f, 0.f};
#pragma unroll
  for (int sk = 0; sk < KSPLIT; ++sk) {
    float4 a = *(const float4*)(yp + ((size_t)sk * (TOK * 2) + i0) * DIM + d);
    float4 b = *(const float4*)(yp + ((size_t)sk * (TOK * 2) + i1) * DIM + d);
    s.x += a.x + b.x; s.y += a.y + b.y; s.z += a.z + b.z; s.w += a.w + b.w;
  }
  *(float4*)(out + (size_t)t * DIM + d) = s;
}

extern "C" void kernel_launch(void* const* d_in, const int* in_sizes, int n_in,
                              void* d_out, int out_size, void* d_ws, size_t ws_size,
                              hipStream_t stream) {
  const float* x      = (const float*)d_in[0];
  const float* noise  = (const float*)d_in[1];
  const float* gate_w = (const float*)d_in[2];
  const float* nw     = (const float*)d_in[3];
  const float* w1     = (const float*)d_in[4];
  const float* b1     = (const float*)d_in[5];
  const float* w2     = (const float*)d_in[6];
  const float* b2     = (const float*)d_in[7];
  const float* wp     = (const float*)d_in[8];
  const float* bp     = (const float*)d_in[9];
  float* out = (float*)d_out;
  char* ws = (char*)d_ws;

  const size_t SZ_X16 = (size_t)TOK * DIM * 2;
  const size_t SZ_ACT = (size_t)TOK * 2 * HID * 2;
  const size_t SZ_W   = (size_t)NE * HID * DIM * 2;

  u16* x16 = (u16*)ws;
  u16* act = (u16*)(ws + SZ_X16);
  u16* w1b = (u16*)(ws + SZ_X16 + SZ_ACT);
  u16* w2b = (u16*)(ws + SZ_X16 + SZ_ACT + SZ_W);
  u16* wpb = (u16*)(ws + SZ_X16 + SZ_ACT + 2 * SZ_W);
  float* yp = (float*)w1b;   // overlays w1b (dead after gemm1)
  char* meta = ws + SZ_X16 + SZ_ACT + 3 * SZ_W;
  int*   tok_e    = (int*)(meta);
  float* tok_w    = (float*)(meta + 16384);
  int*   ent      = (int*)(meta + 32768);
  float* entw     = (float*)(meta + 49152);
  int*   bhist    = (int*)(meta + 65536);
  float* bgw      = (float*)(meta + 81920);
  int*   blk_off  = (int*)(meta + 98304);
  int*   inv      = (int*)(meta + 114688);
  int*   counts   = (int*)(meta + 131072);
  int*   prefix   = (int*)(meta + 131072 + 64);
  int*   tile_tab = (int*)(meta + 131072 + 128);

  k_gate<<<TOK / 4 + NCAST, 256, 0, stream>>>(x, noise, gate_w, nw, w1, w2, wp,
                                              w1b, w2b, wpb, tok_e, tok_w, bhist, bgw, x16);
  k_scan<<<1, 512, 0, stream>>>(bhist, bgw, blk_off, prefix, counts, tile_tab,
                                out + (size_t)TOK * DIM);
  k_build<<<TOK / 256, 256, 0, stream>>>(tok_e, tok_w, prefix, blk_off, ent, entw, inv);
  k_gemm1f<<<dim3(HID / 128, TMAX), 512, 0, stream>>>(x16, w1b, w2b, b1, b2, ent,
                                                      counts, prefix, tile_tab, act);
  k_gemm2f<<<dim3(DIM / 256, TMAX, KSPLIT), 512, 0, stream>>>(act, wpb, bp, entw,
                                                              counts, prefix, tile_tab, yp);
  k_final<<<TOK, 256, 0, stream>>>(yp, inv, out);
}

// Round 9
// 395.417 us; speedup vs baseline: 1.0319x; 1.0319x over previous
//
#include <hip/hip_runtime.h>

#define TOK 2048
#define DIM 1024
#define HID 4096
#define NE 8
#define KSPLIT 4
#define TMAX 24
#define NCAST 2048

typedef unsigned short u16;
typedef __attribute__((ext_vector_type(8))) short s16x8;
typedef __attribute__((ext_vector_type(4))) float f32x4;

__device__ __forceinline__ u16 f2b(float f) {
  unsigned u = __builtin_bit_cast(unsigned, f);
  unsigned r = (u + 0x7fffu + ((u >> 16) & 1u)) >> 16;
  return (u16)r;
}

__device__ __forceinline__ void gld_lds16(const void* g, void* l) {
  __builtin_amdgcn_global_load_lds((const __attribute__((address_space(1))) void*)g,
                                   (__attribute__((address_space(3))) void*)l, 16, 0, 0);
}

// ---------------- gating (blocks 0..511) + w1/w2/wp bf16 cast (blocks 512..512+NCAST) ----------------
__global__ __launch_bounds__(256) void k_gate(const float* __restrict__ x,
    const float* __restrict__ noise, const float* __restrict__ gw,
    const float* __restrict__ nw, const float* __restrict__ w1,
    const float* __restrict__ w2, const float* __restrict__ wp,
    u16* __restrict__ w1b, u16* __restrict__ w2b, u16* __restrict__ wpb,
    int* __restrict__ tok_e, float* __restrict__ tok_w,
    int* __restrict__ bhist, float* __restrict__ bgw, u16* __restrict__ x16) {
  if (blockIdx.x >= TOK / 4) {
    // coalesced cast with batched loads: per tensor, 16 independent dwordx4 loads
    // (8 wave-stride chunks), THEN 8 stores. Store-wait amortized 8x; full MLP.
    const int cb = blockIdx.x - TOK / 4;                 // 0..NCAST-1
    const size_t tbase = ((size_t)cb * 256 + threadIdx.x) * 8;
    const size_t stride = (size_t)NCAST * 256 * 8;       // 4,194,304 floats
    // NPT = NCAST*256*8*8 exactly -> 8 chunks per tensor, no bounds checks
#pragma unroll
    for (int tz = 0; tz < 3; ++tz) {
      const float* in = (tz == 0) ? w1 : (tz == 1) ? w2 : wp;
      u16* o = (tz == 0) ? w1b : (tz == 1) ? w2b : wpb;
      f32x4 f[16];
#pragma unroll
      for (int it = 0; it < 8; ++it) {
        f[it * 2]     = *(const f32x4*)(in + tbase + (size_t)it * stride);
        f[it * 2 + 1] = *(const f32x4*)(in + tbase + (size_t)it * stride + 4);
      }
#pragma unroll
      for (int it = 0; it < 8; ++it) {
        u16 u[8];
        u[0] = f2b(f[it * 2][0]); u[1] = f2b(f[it * 2][1]);
        u[2] = f2b(f[it * 2][2]); u[3] = f2b(f[it * 2][3]);
        u[4] = f2b(f[it * 2 + 1][0]); u[5] = f2b(f[it * 2 + 1][1]);
        u[6] = f2b(f[it * 2 + 1][2]); u[7] = f2b(f[it * 2 + 1][3]);
        *(s16x8*)(o + tbase + (size_t)it * stride) = *(const s16x8*)u;
      }
    }
    return;
  }
  const int wid = threadIdx.x >> 6, lane = threadIdx.x & 63;
  const int t = blockIdx.x * 4 + wid;
  const float* xr = x + (size_t)t * DIM + lane * 16;
  float acc[NE];
#pragma unroll
  for (int e = 0; e < NE; ++e) acc[e] = 0.f;
  u16 xb[16];
#pragma unroll
  for (int j = 0; j < 4; ++j) {
    float4 xv = *(const float4*)(xr + j * 4);
    xb[j * 4 + 0] = f2b(xv.x); xb[j * 4 + 1] = f2b(xv.y);
    xb[j * 4 + 2] = f2b(xv.z); xb[j * 4 + 3] = f2b(xv.w);
#pragma unroll
    for (int e = 0; e < NE; ++e) {
      float4 gv = *(const float4*)(gw + e * DIM + lane * 16 + j * 4);
      acc[e] += xv.x * gv.x + xv.y * gv.y + xv.z * gv.z + xv.w * gv.w;
    }
  }
  *(s16x8*)(x16 + (size_t)t * DIM + lane * 16) = *(const s16x8*)xb;
  *(s16x8*)(x16 + (size_t)t * DIM + lane * 16 + 8) = *(const s16x8*)(xb + 8);
#pragma unroll
  for (int e = 0; e < NE; ++e) {
#pragma unroll
    for (int off = 32; off >= 1; off >>= 1) acc[e] += __shfl_xor(acc[e], off);
  }
  float m = acc[0];
#pragma unroll
  for (int e = 1; e < NE; ++e) m = fmaxf(m, acc[e]);
  float p[NE]; float s = 0.f;
#pragma unroll
  for (int e = 0; e < NE; ++e) { p[e] = expf(acc[e] - m); s += p[e]; }
  float inv = 1.f / s;
  float v[NE];
#pragma unroll
  for (int e = 0; e < NE; ++e) v[e] = acc[e] + noise[t * NE + e] * nw[e];
  float v0 = -3.4e38f, v1 = -3.4e38f; int i0 = 0, i1 = 0;
#pragma unroll
  for (int e = 0; e < NE; ++e) {
    float ve = v[e];
    if (ve > v0) { v1 = v0; i1 = i0; v0 = ve; i0 = e; }
    else if (ve > v1) { v1 = ve; i1 = e; }
  }
  float e1 = expf(v1 - v0);
  float den = 1.f + e1;
  float w0 = 1.f / den, w1v = e1 / den;

  __shared__ float pl[4][NE];
  __shared__ int el[4][2];
  if (lane == 0) {
#pragma unroll
    for (int e = 0; e < NE; ++e) pl[wid][e] = p[e] * inv;
    el[wid][0] = i0; el[wid][1] = i1;
    tok_e[t * 2] = i0; tok_e[t * 2 + 1] = i1;
    tok_w[t * 2] = w0; tok_w[t * 2 + 1] = w1v;
  }
  __syncthreads();
  if (threadIdx.x < NE) {
    const int e = threadIdx.x;
    float ps = pl[0][e] + pl[1][e] + pl[2][e] + pl[3][e];
    int h = 0;
#pragma unroll
    for (int j = 0; j < 4; ++j) {
      h += (el[j][0] == e);
      h += (el[j][1] == e);
    }
    bgw[blockIdx.x * NE + e] = ps;
    bhist[blockIdx.x * NE + e] = h;
  }
}

// ---------------- scan: offsets, counts, prefix, 256-row tile table, lb loss ----------------
__global__ __launch_bounds__(512) void k_scan(const int* __restrict__ bhist,
    const float* __restrict__ bgw, int* __restrict__ blk_off, int* __restrict__ prefix,
    int* __restrict__ counts, int* __restrict__ tile_tab, float* __restrict__ loss_out) {
  const int i = threadIdx.x, lane = i & 63, wv = i >> 6;
  __shared__ int wsum[8];
  __shared__ float wfs[8];
  __shared__ int etot[8];
  __shared__ float fsum[8];
  for (int e = 0; e < NE; ++e) {
    int v = bhist[i * NE + e];
    int sc = v;
#pragma unroll
    for (int off = 1; off < 64; off <<= 1) {
      int u = __shfl_up(sc, off);
      if (lane >= off) sc += u;
    }
    float f = bgw[i * NE + e];
#pragma unroll
    for (int off = 32; off >= 1; off >>= 1) f += __shfl_xor(f, off);
    if (lane == 63) wsum[wv] = sc;
    if (lane == 0) wfs[wv] = f;
    __syncthreads();
    int base = 0;
    for (int w2 = 0; w2 < wv; ++w2) base += wsum[w2];
    blk_off[i * NE + e] = base + sc - v;
    if (i == 0) {
      float tf = 0.f;
      for (int w2 = 0; w2 < 8; ++w2) tf += wfs[w2];
      fsum[e] = tf;
    }
    if (i == 511) etot[e] = base + sc;
    __syncthreads();
  }
  if (i == 0) {
    int sacc = 0;
    float l = 0.f;
    int tt = 0;
#pragma unroll
    for (int e = 0; e < NE; ++e) { prefix[e] = sacc; counts[e] = etot[e]; sacc += etot[e]; }
    for (int e = 0; e < NE; ++e) {
      const int nmt = (etot[e] + 255) >> 8;
      for (int m2 = 0; m2 < nmt; ++m2) tile_tab[tt++] = (e << 16) | m2;
    }
    for (; tt < TMAX; ++tt) tile_tab[tt] = -1;
#pragma unroll
    for (int e = 0; e < NE; ++e) {
      float d = fsum[e] * (1.f / TOK) - 0.125f;
      l += d * d;
    }
    *loss_out = l * (0.01f / NE);
  }
}

// ---------------- build compacted expert lists + inverse map ----------------
__global__ __launch_bounds__(256) void k_build(const int* __restrict__ tok_e,
    const float* __restrict__ tok_w, const int* __restrict__ prefix,
    const int* __restrict__ blk_off, int* __restrict__ ent, float* __restrict__ entw,
    int* __restrict__ inv) {
  const int t = blockIdx.x * 256 + threadIdx.x;
  const int g = t >> 2;
  const int base = (t & 3) * 2;
  int ee[8];
#pragma unroll
  for (int j = 0; j < 8; ++j) ee[j] = tok_e[g * 8 + j];
#pragma unroll
  for (int s = 0; s < 2; ++s) {
    const int e = ee[base + s];
    int rank = 0;
#pragma unroll
    for (int j = 0; j < 8; ++j) rank += (j < base + s) && (ee[j] == e);
    const int idx = prefix[e] + blk_off[g * NE + e] + rank;
    ent[idx] = t * 2 + s;
    entw[idx] = tok_w[t * 2 + s];
    inv[t * 2 + s] = idx;
  }
}

// ================= GEMM1: 256x128 tile, 8 waves, counted-vmcnt depth-2 pipeline =================
__global__ __launch_bounds__(512) void k_gemm1f(const u16* __restrict__ x16,
    const u16* __restrict__ w1b, const u16* __restrict__ w2b,
    const float* __restrict__ b1, const float* __restrict__ b2,
    const int* __restrict__ ent, const int* __restrict__ counts,
    const int* __restrict__ prefix, const int* __restrict__ tile_tab,
    u16* __restrict__ act) {
  const int tt = tile_tab[blockIdx.y];
  if (tt < 0) return;
  const int e = tt >> 16, mt = tt & 0xffff, nt = blockIdx.x;
  const int cnt = counts[e];
  const int pfx = prefix[e];
  const int tid = threadIdx.x, w = tid >> 6, l = tid & 63;

  __shared__ u16 smem[2][16384];   // A: [0,8192) 256x32, B1: [8192,12288), B2: [12288,16384)

  const int r0 = tid >> 2;
  const int c = (tid & 3) ^ ((tid >> 3) & 3);
  int g0 = mt * 256 + r0;       if (g0 >= cnt) g0 = cnt - 1;
  int g1 = mt * 256 + 128 + r0; if (g1 >= cnt) g1 = cnt - 1;
  const u16* sa0 = x16 + (size_t)(ent[pfx + g0] >> 1) * DIM + c * 8;
  const u16* sa1 = x16 + (size_t)(ent[pfx + g1] >> 1) * DIM + c * 8;
  const u16* sb1 = w1b + ((size_t)e * HID + nt * 128 + r0) * DIM + c * 8;
  const u16* sb2 = w2b + ((size_t)e * HID + nt * 128 + r0) * DIM + c * 8;
  const int oA0 = tid * 8, oA1 = 4096 + tid * 8;
  const int oB1 = 8192 + tid * 8, oB2 = 12288 + tid * 8;

  const int wr = w >> 1, wc = w & 1;
  const int xs = ((l >> 4) ^ ((l >> 1) & 3)) * 8;
  const int ra = (wr * 64 + (l & 15)) * 32 + xs;
  const int rb = (wc * 64 + (l & 15)) * 32 + xs;

  f32x4 acc1[4][4], acc2[4][4];
#pragma unroll
  for (int m = 0; m < 4; ++m)
#pragma unroll
    for (int n = 0; n < 4; ++n) {
      acc1[m][n] = (f32x4){0.f, 0.f, 0.f, 0.f};
      acc2[m][n] = (f32x4){0.f, 0.f, 0.f, 0.f};
    }

  auto STAGE = [&](int buf, int k0) {
    gld_lds16(sa0 + k0, &smem[buf][oA0]);
    gld_lds16(sa1 + k0, &smem[buf][oA1]);
    gld_lds16(sb1 + k0, &smem[buf][oB1]);
    gld_lds16(sb2 + k0, &smem[buf][oB2]);
  };

  const int NT = DIM / 32;
  STAGE(0, 0);
  STAGE(1, 32);
  asm volatile("s_waitcnt vmcnt(4)" ::: "memory");
  __builtin_amdgcn_s_barrier();
  __builtin_amdgcn_sched_barrier(0);
  int cur = 0;
  for (int kt = 0; kt < NT; ++kt) {
    const u16* S = &smem[cur][0];
    s16x8 af[4];
#pragma unroll
    for (int m = 0; m < 4; ++m) af[m] = *(const s16x8*)(S + ra + m * 512);
#pragma unroll
    for (int n = 0; n < 4; ++n) {
      s16x8 bf1 = *(const s16x8*)(S + 8192 + rb + n * 512);
      s16x8 bf2 = *(const s16x8*)(S + 12288 + rb + n * 512);
#pragma unroll
      for (int m = 0; m < 4; ++m) {
        acc1[m][n] = __builtin_amdgcn_mfma_f32_16x16x32_bf16(af[m], bf1, acc1[m][n], 0, 0, 0);
        acc2[m][n] = __builtin_amdgcn_mfma_f32_16x16x32_bf16(af[m], bf2, acc2[m][n], 0, 0, 0);
      }
    }
    if (kt + 1 < NT) {
      asm volatile("s_waitcnt lgkmcnt(0)" ::: "memory");
      __builtin_amdgcn_sched_barrier(0);
      __builtin_amdgcn_s_barrier();            // all waves done reading smem[cur]
      if (kt + 2 < NT) {
        STAGE(cur, (kt + 2) * 32);             // overwrite with tile kt+2
        asm volatile("s_waitcnt vmcnt(4)" ::: "memory");   // tile kt+1 arrived
      } else {
        asm volatile("s_waitcnt vmcnt(0)" ::: "memory");
      }
      __builtin_amdgcn_s_barrier();            // all waves see tile kt+1
      __builtin_amdgcn_sched_barrier(0);
    }
    cur ^= 1;
  }

#pragma unroll
  for (int n = 0; n < 4; ++n) {
    const int col = nt * 128 + wc * 64 + n * 16 + (l & 15);
    const float bb1 = b1[(size_t)e * HID + col];
    const float bb2 = b2[(size_t)e * HID + col];
#pragma unroll
    for (int m = 0; m < 4; ++m) {
#pragma unroll
      for (int r = 0; r < 4; ++r) {
        const int row = mt * 256 + wr * 64 + m * 16 + (l >> 4) * 4 + r;
        if (row < cnt) {
          float h = acc1[m][n][r] + bb1;
          float g = acc2[m][n][r] + bb2;
          float a = h * g / (1.f + expf(-g));
          act[(size_t)(pfx + row) * HID + col] = f2b(a);
        }
      }
    }
  }
}

// ================= GEMM2: 256x256 tile, 8 waves, split-K=4, counted-vmcnt pipeline =================
__global__ __launch_bounds__(512) void k_gemm2f(const u16* __restrict__ act,
    const u16* __restrict__ wpb, const float* __restrict__ bp,
    const float* __restrict__ entw, const int* __restrict__ counts,
    const int* __restrict__ prefix, const int* __restrict__ tile_tab,
    float* __restrict__ yp) {
  const int tt = tile_tab[blockIdx.y];
  if (tt < 0) return;
  const int e = tt >> 16, mt = tt & 0xffff;
  const int sk = blockIdx.z, nt = blockIdx.x;
  const int cnt = counts[e];
  const int pfx = prefix[e];
  const int tid = threadIdx.x, w = tid >> 6, l = tid & 63;

  __shared__ u16 smem[2][16384];

  const int r0 = tid >> 2;
  const int c = (tid & 3) ^ ((tid >> 3) & 3);
  int g0 = mt * 256 + r0;       if (g0 >= cnt) g0 = cnt - 1;
  int g1 = mt * 256 + 128 + r0; if (g1 >= cnt) g1 = cnt - 1;
  const int kbase = sk * (HID / KSPLIT);
  const u16* sa0 = act + (size_t)(pfx + g0) * HID + kbase + c * 8;
  const u16* sa1 = act + (size_t)(pfx + g1) * HID + kbase + c * 8;
  const u16* sb0 = wpb + ((size_t)e * DIM + nt * 256 + r0) * HID + kbase + c * 8;
  const u16* sb1 = sb0 + (size_t)128 * HID;
  const int oA0 = tid * 8, oA1 = 4096 + tid * 8;
  const int oB0 = 8192 + tid * 8, oB1 = 12288 + tid * 8;

  const int wr = w >> 2, wc = w & 3;
  const int xs = ((l >> 4) ^ ((l >> 1) & 3)) * 8;
  const int ra = (wr * 128 + (l & 15)) * 32 + xs;
  const int rb = 8192 + (wc * 64 + (l & 15)) * 32 + xs;

  f32x4 acc[8][4];
#pragma unroll
  for (int m = 0; m < 8; ++m)
#pragma unroll
    for (int n = 0; n < 4; ++n) acc[m][n] = (f32x4){0.f, 0.f, 0.f, 0.f};

  auto STAGE = [&](int buf, int k0) {
    gld_lds16(sa0 + k0, &smem[buf][oA0]);
    gld_lds16(sa1 + k0, &smem[buf][oA1]);
    gld_lds16(sb0 + k0, &smem[buf][oB0]);
    gld_lds16(sb1 + k0, &smem[buf][oB1]);
  };

  const int NIT = HID / KSPLIT / 32;
  STAGE(0, 0);
  STAGE(1, 32);
  asm volatile("s_waitcnt vmcnt(4)" ::: "memory");
  __builtin_amdgcn_s_barrier();
  __builtin_amdgcn_sched_barrier(0);
  int cur = 0;
  for (int kt = 0; kt < NIT; ++kt) {
    const u16* S = &smem[cur][0];
#pragma unroll
    for (int n = 0; n < 4; ++n) {
      s16x8 bf = *(const s16x8*)(S + rb + n * 512);
#pragma unroll
      for (int m = 0; m < 8; ++m) {
        s16x8 af = *(const s16x8*)(S + ra + m * 512);
        acc[m][n] = __builtin_amdgcn_mfma_f32_16x16x32_bf16(af, bf, acc[m][n], 0, 0, 0);
      }
    }
    if (kt + 1 < NIT) {
      asm volatile("s_waitcnt lgkmcnt(0)" ::: "memory");
      __builtin_amdgcn_sched_barrier(0);
      __builtin_amdgcn_s_barrier();
      if (kt + 2 < NIT) {
        STAGE(cur, (kt + 2) * 32);
        asm volatile("s_waitcnt vmcnt(4)" ::: "memory");
      } else {
        asm volatile("s_waitcnt vmcnt(0)" ::: "memory");
      }
      __builtin_amdgcn_s_barrier();
      __builtin_amdgcn_sched_barrier(0);
    }
    cur ^= 1;
  }

#pragma unroll
  for (int n = 0; n < 4; ++n) {
    const int col = nt * 256 + wc * 64 + n * 16 + (l & 15);
    const float bpv = (sk == 0) ? bp[(size_t)e * DIM + col] : 0.f;
#pragma unroll
    for (int m = 0; m < 8; ++m) {
#pragma unroll
      for (int r = 0; r < 4; ++r) {
        const int row = mt * 256 + wr * 128 + m * 16 + (l >> 4) * 4 + r;
        if (row < cnt) {
          const int idx = pfx + row;
          yp[((size_t)sk * (TOK * 2) + idx) * DIM + col] = entw[idx] * (acc[m][n][r] + bpv);
        }
      }
    }
  }
}

// ---------------- final: out[t] = sum over 2 slots x KSPLIT partials ----------------
__global__ __launch_bounds__(256) void k_final(const float* __restrict__ yp,
    const int* __restrict__ inv, float* __restrict__ out) {
  const int t = blockIdx.x;
  const int d = threadIdx.x * 4;
  const int i0 = inv[t * 2], i1 = inv[t * 2 + 1];
  float4 s = {0.f, 0.f, 0.f, 0.f};
#pragma unroll
  for (int sk = 0; sk < KSPLIT; ++sk) {
    float4 a = *(const float4*)(yp + ((size_t)sk * (TOK * 2) + i0) * DIM + d);
    float4 b = *(const float4*)(yp + ((size_t)sk * (TOK * 2) + i1) * DIM + d);
    s.x += a.x + b.x; s.y += a.y + b.y; s.z += a.z + b.z; s.w += a.w + b.w;
  }
  *(float4*)(out + (size_t)t * DIM + d) = s;
}

extern "C" void kernel_launch(void* const* d_in, const int* in_sizes, int n_in,
                              void* d_out, int out_size, void* d_ws, size_t ws_size,
                              hipStream_t stream) {
  const float* x      = (const float*)d_in[0];
  const float* noise  = (const float*)d_in[1];
  const float* gate_w = (const float*)d_in[2];
  const float* nw     = (const float*)d_in[3];
  const float* w1     = (const float*)d_in[4];
  const float* b1     = (const float*)d_in[5];
  const float* w2     = (const float*)d_in[6];
  const float* b2     = (const float*)d_in[7];
  const float* wp     = (const float*)d_in[8];
  const float* bp     = (const float*)d_in[9];
  float* out = (float*)d_out;
  char* ws = (char*)d_ws;

  const size_t SZ_X16 = (size_t)TOK * DIM * 2;
  const size_t SZ_ACT = (size_t)TOK * 2 * HID * 2;
  const size_t SZ_W   = (size_t)NE * HID * DIM * 2;

  u16* x16 = (u16*)ws;
  u16* act = (u16*)(ws + SZ_X16);
  u16* w1b = (u16*)(ws + SZ_X16 + SZ_ACT);
  u16* w2b = (u16*)(ws + SZ_X16 + SZ_ACT + SZ_W);
  u16* wpb = (u16*)(ws + SZ_X16 + SZ_ACT + 2 * SZ_W);
  float* yp = (float*)w1b;   // overlays w1b (dead after gemm1)
  char* meta = ws + SZ_X16 + SZ_ACT + 3 * SZ_W;
  int*   tok_e    = (int*)(meta);
  float* tok_w    = (float*)(meta + 16384);
  int*   ent      = (int*)(meta + 32768);
  float* entw     = (float*)(meta + 49152);
  int*   bhist    = (int*)(meta + 65536);
  float* bgw      = (float*)(meta + 81920);
  int*   blk_off  = (int*)(meta + 98304);
  int*   inv      = (int*)(meta + 114688);
  int*   counts   = (int*)(meta + 131072);
  int*   prefix   = (int*)(meta + 131072 + 64);
  int*   tile_tab = (int*)(meta + 131072 + 128);

  k_gate<<<TOK / 4 + NCAST, 256, 0, stream>>>(x, noise, gate_w, nw, w1, w2, wp,
                                              w1b, w2b, wpb, tok_e, tok_w, bhist, bgw, x16);
  k_scan<<<1, 512, 0, stream>>>(bhist, bgw, blk_off, prefix, counts, tile_tab,
                                out + (size_t)TOK * DIM);
  k_build<<<TOK / 256, 256, 0, stream>>>(tok_e, tok_w, prefix, blk_off, ent, entw, inv);
  k_gemm1f<<<dim3(HID / 128, TMAX), 512, 0, stream>>>(x16, w1b, w2b, b1, b2, ent,
                                                      counts, prefix, tile_tab, act);
  k_gemm2f<<<dim3(DIM / 256, TMAX, KSPLIT), 512, 0, stream>>>(act, wpb, bp, entw,
                                                              counts, prefix, tile_tab, yp);
  k_final<<<TOK, 256, 0, stream>>>(yp, inv, out);
}

// Round 10
// 366.629 us; speedup vs baseline: 1.1129x; 1.0785x over previous
//
#include <hip/hip_runtime.h>

#define TOK 2048
#define DIM 1024
#define HID 4096
#define NE 8
#define KSPLIT 4
#define TMAX 24

typedef unsigned short u16;
typedef __attribute__((ext_vector_type(8))) short s16x8;
typedef __attribute__((ext_vector_type(4))) float f32x4;

__device__ __forceinline__ u16 f2b(float f) {
  unsigned u = __builtin_bit_cast(unsigned, f);
  unsigned r = (u + 0x7fffu + ((u >> 16) & 1u)) >> 16;
  return (u16)r;
}

__device__ __forceinline__ void gld_lds16(const void* g, void* l) {
  __builtin_amdgcn_global_load_lds((const __attribute__((address_space(1))) void*)g,
                                   (__attribute__((address_space(3))) void*)l, 16, 0, 0);
}

// ---------------- gating: one wave per token (512 blocks) ----------------
__global__ __launch_bounds__(256) void k_gate(const float* __restrict__ x,
    const float* __restrict__ noise, const float* __restrict__ gw,
    const float* __restrict__ nw,
    int* __restrict__ tok_e, float* __restrict__ tok_w,
    int* __restrict__ bhist, float* __restrict__ bgw, u16* __restrict__ x16) {
  const int wid = threadIdx.x >> 6, lane = threadIdx.x & 63;
  const int t = blockIdx.x * 4 + wid;
  const float* xr = x + (size_t)t * DIM + lane * 16;
  float acc[NE];
#pragma unroll
  for (int e = 0; e < NE; ++e) acc[e] = 0.f;
  u16 xb[16];
#pragma unroll
  for (int j = 0; j < 4; ++j) {
    float4 xv = *(const float4*)(xr + j * 4);
    xb[j * 4 + 0] = f2b(xv.x); xb[j * 4 + 1] = f2b(xv.y);
    xb[j * 4 + 2] = f2b(xv.z); xb[j * 4 + 3] = f2b(xv.w);
#pragma unroll
    for (int e = 0; e < NE; ++e) {
      float4 gv = *(const float4*)(gw + e * DIM + lane * 16 + j * 4);
      acc[e] += xv.x * gv.x + xv.y * gv.y + xv.z * gv.z + xv.w * gv.w;
    }
  }
  *(s16x8*)(x16 + (size_t)t * DIM + lane * 16) = *(const s16x8*)xb;
  *(s16x8*)(x16 + (size_t)t * DIM + lane * 16 + 8) = *(const s16x8*)(xb + 8);
#pragma unroll
  for (int e = 0; e < NE; ++e) {
#pragma unroll
    for (int off = 32; off >= 1; off >>= 1) acc[e] += __shfl_xor(acc[e], off);
  }
  float m = acc[0];
#pragma unroll
  for (int e = 1; e < NE; ++e) m = fmaxf(m, acc[e]);
  float p[NE]; float s = 0.f;
#pragma unroll
  for (int e = 0; e < NE; ++e) { p[e] = expf(acc[e] - m); s += p[e]; }
  float inv = 1.f / s;
  float v[NE];
#pragma unroll
  for (int e = 0; e < NE; ++e) v[e] = acc[e] + noise[t * NE + e] * nw[e];
  float v0 = -3.4e38f, v1 = -3.4e38f; int i0 = 0, i1 = 0;
#pragma unroll
  for (int e = 0; e < NE; ++e) {
    float ve = v[e];
    if (ve > v0) { v1 = v0; i1 = i0; v0 = ve; i0 = e; }
    else if (ve > v1) { v1 = ve; i1 = e; }
  }
  float e1 = expf(v1 - v0);
  float den = 1.f + e1;
  float w0 = 1.f / den, w1v = e1 / den;

  __shared__ float pl[4][NE];
  __shared__ int el[4][2];
  if (lane == 0) {
#pragma unroll
    for (int e = 0; e < NE; ++e) pl[wid][e] = p[e] * inv;
    el[wid][0] = i0; el[wid][1] = i1;
    tok_e[t * 2] = i0; tok_e[t * 2 + 1] = i1;
    tok_w[t * 2] = w0; tok_w[t * 2 + 1] = w1v;
  }
  __syncthreads();
  if (threadIdx.x < NE) {
    const int e = threadIdx.x;
    float ps = pl[0][e] + pl[1][e] + pl[2][e] + pl[3][e];
    int h = 0;
#pragma unroll
    for (int j = 0; j < 4; ++j) {
      h += (el[j][0] == e);
      h += (el[j][1] == e);
    }
    bgw[blockIdx.x * NE + e] = ps;
    bhist[blockIdx.x * NE + e] = h;
  }
}

// ---------------- scan: offsets, counts, prefix, 256-row tile table, lb loss ----------------
__global__ __launch_bounds__(512) void k_scan(const int* __restrict__ bhist,
    const float* __restrict__ bgw, int* __restrict__ blk_off, int* __restrict__ prefix,
    int* __restrict__ counts, int* __restrict__ tile_tab, float* __restrict__ loss_out) {
  const int i = threadIdx.x, lane = i & 63, wv = i >> 6;
  __shared__ int wsum[8];
  __shared__ float wfs[8];
  __shared__ int etot[8];
  __shared__ float fsum[8];
  for (int e = 0; e < NE; ++e) {
    int v = bhist[i * NE + e];
    int sc = v;
#pragma unroll
    for (int off = 1; off < 64; off <<= 1) {
      int u = __shfl_up(sc, off);
      if (lane >= off) sc += u;
    }
    float f = bgw[i * NE + e];
#pragma unroll
    for (int off = 32; off >= 1; off >>= 1) f += __shfl_xor(f, off);
    if (lane == 63) wsum[wv] = sc;
    if (lane == 0) wfs[wv] = f;
    __syncthreads();
    int base = 0;
    for (int w2 = 0; w2 < wv; ++w2) base += wsum[w2];
    blk_off[i * NE + e] = base + sc - v;
    if (i == 0) {
      float tf = 0.f;
      for (int w2 = 0; w2 < 8; ++w2) tf += wfs[w2];
      fsum[e] = tf;
    }
    if (i == 511) etot[e] = base + sc;
    __syncthreads();
  }
  if (i == 0) {
    int sacc = 0;
    float l = 0.f;
    int tt = 0;
#pragma unroll
    for (int e = 0; e < NE; ++e) { prefix[e] = sacc; counts[e] = etot[e]; sacc += etot[e]; }
    for (int e = 0; e < NE; ++e) {
      const int nmt = (etot[e] + 255) >> 8;
      for (int m2 = 0; m2 < nmt; ++m2) tile_tab[tt++] = (e << 16) | m2;
    }
    for (; tt < TMAX; ++tt) tile_tab[tt] = -1;
#pragma unroll
    for (int e = 0; e < NE; ++e) {
      float d = fsum[e] * (1.f / TOK) - 0.125f;
      l += d * d;
    }
    *loss_out = l * (0.01f / NE);
  }
}

// ---------------- build compacted expert lists + inverse map ----------------
__global__ __launch_bounds__(256) void k_build(const int* __restrict__ tok_e,
    const float* __restrict__ tok_w, const int* __restrict__ prefix,
    const int* __restrict__ blk_off, int* __restrict__ ent, float* __restrict__ entw,
    int* __restrict__ inv) {
  const int t = blockIdx.x * 256 + threadIdx.x;
  const int g = t >> 2;
  const int base = (t & 3) * 2;
  int ee[8];
#pragma unroll
  for (int j = 0; j < 8; ++j) ee[j] = tok_e[g * 8 + j];
#pragma unroll
  for (int s = 0; s < 2; ++s) {
    const int e = ee[base + s];
    int rank = 0;
#pragma unroll
    for (int j = 0; j < 8; ++j) rank += (j < base + s) && (ee[j] == e);
    const int idx = prefix[e] + blk_off[g * NE + e] + rank;
    ent[idx] = t * 2 + s;
    entw[idx] = tok_w[t * 2 + s];
    inv[t * 2 + s] = idx;
  }
}

// ====== GEMM1: 256x128 tile, 8 waves, fp32 weights inline-cast (T14 reg-stage), dbuf ======
__global__ __launch_bounds__(512) void k_gemm1f(const u16* __restrict__ x16,
    const float* __restrict__ w1, const float* __restrict__ w2,
    const float* __restrict__ b1, const float* __restrict__ b2,
    const int* __restrict__ ent, const int* __restrict__ counts,
    const int* __restrict__ prefix, const int* __restrict__ tile_tab,
    u16* __restrict__ act) {
  const int tt = tile_tab[blockIdx.y];
  if (tt < 0) return;
  const int e = tt >> 16, mt = tt & 0xffff, nt = blockIdx.x;
  const int cnt = counts[e];
  const int pfx = prefix[e];
  const int tid = threadIdx.x, w = tid >> 6, l = tid & 63;

  __shared__ u16 smem[2][16384];   // A: [0,8192) 256x32, B1: [8192,12288), B2: [12288,16384)

  const int r0 = tid >> 2;                          // 0..127
  const int c = (tid & 3) ^ ((tid >> 3) & 3);       // swizzled source chunk
  int g0 = mt * 256 + r0;       if (g0 >= cnt) g0 = cnt - 1;
  int g1 = mt * 256 + 128 + r0; if (g1 >= cnt) g1 = cnt - 1;
  const u16* sa0 = x16 + (size_t)(ent[pfx + g0] >> 1) * DIM + c * 8;
  const u16* sa1 = x16 + (size_t)(ent[pfx + g1] >> 1) * DIM + c * 8;
  const float* pB1 = w1 + ((size_t)e * HID + nt * 128 + r0) * DIM + c * 8;
  const float* pB2 = w2 + ((size_t)e * HID + nt * 128 + r0) * DIM + c * 8;
  const int oA0 = tid * 8, oA1 = 4096 + tid * 8;
  const int oB1 = 8192 + tid * 8, oB2 = 12288 + tid * 8;

  const int wr = w >> 1, wc = w & 1;
  const int xs = ((l >> 4) ^ ((l >> 1) & 3)) * 8;
  const int ra = (wr * 64 + (l & 15)) * 32 + xs;
  const int rb = (wc * 64 + (l & 15)) * 32 + xs;

  f32x4 acc1[4][4], acc2[4][4];
#pragma unroll
  for (int m = 0; m < 4; ++m)
#pragma unroll
    for (int n = 0; n < 4; ++n) {
      acc1[m][n] = (f32x4){0.f, 0.f, 0.f, 0.f};
      acc2[m][n] = (f32x4){0.f, 0.f, 0.f, 0.f};
    }

  f32x4 rb0_, rb1_, rb2_, rb3_;     // in-flight fp32 B (B1 lo/hi, B2 lo/hi)
  auto LOADB = [&](int k0) {
    rb0_ = *(const f32x4*)(pB1 + k0);
    rb1_ = *(const f32x4*)(pB1 + k0 + 4);
    rb2_ = *(const f32x4*)(pB2 + k0);
    rb3_ = *(const f32x4*)(pB2 + k0 + 4);
  };
  auto STAGEA = [&](int buf, int k0) {
    gld_lds16(sa0 + k0, &smem[buf][oA0]);
    gld_lds16(sa1 + k0, &smem[buf][oA1]);
  };
  auto WRITEB = [&](int buf) {
    u16 u[16];
    u[0] = f2b(rb0_[0]); u[1] = f2b(rb0_[1]); u[2] = f2b(rb0_[2]); u[3] = f2b(rb0_[3]);
    u[4] = f2b(rb1_[0]); u[5] = f2b(rb1_[1]); u[6] = f2b(rb1_[2]); u[7] = f2b(rb1_[3]);
    u[8] = f2b(rb2_[0]); u[9] = f2b(rb2_[1]); u[10] = f2b(rb2_[2]); u[11] = f2b(rb2_[3]);
    u[12] = f2b(rb3_[0]); u[13] = f2b(rb3_[1]); u[14] = f2b(rb3_[2]); u[15] = f2b(rb3_[3]);
    *(s16x8*)&smem[buf][oB1] = *(const s16x8*)u;
    *(s16x8*)&smem[buf][oB2] = *(const s16x8*)(u + 8);
  };

  const int NT = DIM / 32;
  LOADB(0);
  STAGEA(0, 0);
  asm volatile("s_waitcnt vmcnt(0)" ::: "memory");
  WRITEB(0);
  asm volatile("s_waitcnt lgkmcnt(0)" ::: "memory");
  __builtin_amdgcn_sched_barrier(0);
  __builtin_amdgcn_s_barrier();
  int cur = 0;
  for (int kt = 0; kt < NT; ++kt) {
    if (kt + 1 < NT) { LOADB((kt + 1) * 32); STAGEA(cur ^ 1, (kt + 1) * 32); }
    const u16* S = &smem[cur][0];
    s16x8 af[4];
#pragma unroll
    for (int m = 0; m < 4; ++m) af[m] = *(const s16x8*)(S + ra + m * 512);
#pragma unroll
    for (int n = 0; n < 4; ++n) {
      s16x8 bf1 = *(const s16x8*)(S + 8192 + rb + n * 512);
      s16x8 bf2 = *(const s16x8*)(S + 12288 + rb + n * 512);
#pragma unroll
      for (int m = 0; m < 4; ++m) {
        acc1[m][n] = __builtin_amdgcn_mfma_f32_16x16x32_bf16(af[m], bf1, acc1[m][n], 0, 0, 0);
        acc2[m][n] = __builtin_amdgcn_mfma_f32_16x16x32_bf16(af[m], bf2, acc2[m][n], 0, 0, 0);
      }
    }
    if (kt + 1 < NT) {
      asm volatile("s_waitcnt vmcnt(0)" ::: "memory");   // B regs + next A-tile DMA landed
      __builtin_amdgcn_sched_barrier(0);
      WRITEB(cur ^ 1);
      asm volatile("s_waitcnt lgkmcnt(0)" ::: "memory");
      __builtin_amdgcn_sched_barrier(0);
      __builtin_amdgcn_s_barrier();
    }
    cur ^= 1;
  }

#pragma unroll
  for (int n = 0; n < 4; ++n) {
    const int col = nt * 128 + wc * 64 + n * 16 + (l & 15);
    const float bb1 = b1[(size_t)e * HID + col];
    const float bb2 = b2[(size_t)e * HID + col];
#pragma unroll
    for (int m = 0; m < 4; ++m) {
#pragma unroll
      for (int r = 0; r < 4; ++r) {
        const int row = mt * 256 + wr * 64 + m * 16 + (l >> 4) * 4 + r;
        if (row < cnt) {
          float h = acc1[m][n][r] + bb1;
          float g = acc2[m][n][r] + bb2;
          float a = h * g / (1.f + expf(-g));
          act[(size_t)(pfx + row) * HID + col] = f2b(a);
        }
      }
    }
  }
}

// ====== GEMM2: 256x256 tile, 8 waves, split-K=4, fp32 wp inline-cast, dbuf ======
__global__ __launch_bounds__(512) void k_gemm2f(const u16* __restrict__ act,
    const float* __restrict__ wp, const float* __restrict__ bp,
    const float* __restrict__ entw, const int* __restrict__ counts,
    const int* __restrict__ prefix, const int* __restrict__ tile_tab,
    float* __restrict__ yp) {
  const int tt = tile_tab[blockIdx.y];
  if (tt < 0) return;
  const int e = tt >> 16, mt = tt & 0xffff;
  const int sk = blockIdx.z, nt = blockIdx.x;
  const int cnt = counts[e];
  const int pfx = prefix[e];
  const int tid = threadIdx.x, w = tid >> 6, l = tid & 63;

  __shared__ u16 smem[2][16384];   // A: [0,8192) 256x32, B: [8192,16384) 256x32

  const int r0 = tid >> 2;
  const int c = (tid & 3) ^ ((tid >> 3) & 3);
  int g0 = mt * 256 + r0;       if (g0 >= cnt) g0 = cnt - 1;
  int g1 = mt * 256 + 128 + r0; if (g1 >= cnt) g1 = cnt - 1;
  const int kbase = sk * (HID / KSPLIT);
  const u16* sa0 = act + (size_t)(pfx + g0) * HID + kbase + c * 8;
  const u16* sa1 = act + (size_t)(pfx + g1) * HID + kbase + c * 8;
  const float* pB0 = wp + ((size_t)e * DIM + nt * 256 + r0) * HID + kbase + c * 8;
  const float* pB1h = pB0 + (size_t)128 * HID;
  const int oA0 = tid * 8, oA1 = 4096 + tid * 8;
  const int oB0 = 8192 + tid * 8, oB1 = 12288 + tid * 8;

  const int wr = w >> 2, wc = w & 3;
  const int xs = ((l >> 4) ^ ((l >> 1) & 3)) * 8;
  const int ra = (wr * 128 + (l & 15)) * 32 + xs;
  const int rb = 8192 + (wc * 64 + (l & 15)) * 32 + xs;

  f32x4 acc[8][4];
#pragma unroll
  for (int m = 0; m < 8; ++m)
#pragma unroll
    for (int n = 0; n < 4; ++n) acc[m][n] = (f32x4){0.f, 0.f, 0.f, 0.f};

  f32x4 rb0_, rb1_, rb2_, rb3_;
  auto LOADB = [&](int k0) {
    rb0_ = *(const f32x4*)(pB0 + k0);
    rb1_ = *(const f32x4*)(pB0 + k0 + 4);
    rb2_ = *(const f32x4*)(pB1h + k0);
    rb3_ = *(const f32x4*)(pB1h + k0 + 4);
  };
  auto STAGEA = [&](int buf, int k0) {
    gld_lds16(sa0 + k0, &smem[buf][oA0]);
    gld_lds16(sa1 + k0, &smem[buf][oA1]);
  };
  auto WRITEB = [&](int buf) {
    u16 u[16];
    u[0] = f2b(rb0_[0]); u[1] = f2b(rb0_[1]); u[2] = f2b(rb0_[2]); u[3] = f2b(rb0_[3]);
    u[4] = f2b(rb1_[0]); u[5] = f2b(rb1_[1]); u[6] = f2b(rb1_[2]); u[7] = f2b(rb1_[3]);
    u[8] = f2b(rb2_[0]); u[9] = f2b(rb2_[1]); u[10] = f2b(rb2_[2]); u[11] = f2b(rb2_[3]);
    u[12] = f2b(rb3_[0]); u[13] = f2b(rb3_[1]); u[14] = f2b(rb3_[2]); u[15] = f2b(rb3_[3]);
    *(s16x8*)&smem[buf][oB0] = *(const s16x8*)u;
    *(s16x8*)&smem[buf][oB1] = *(const s16x8*)(u + 8);
  };

  const int NIT = HID / KSPLIT / 32;
  LOADB(0);
  STAGEA(0, 0);
  asm volatile("s_waitcnt vmcnt(0)" ::: "memory");
  WRITEB(0);
  asm volatile("s_waitcnt lgkmcnt(0)" ::: "memory");
  __builtin_amdgcn_sched_barrier(0);
  __builtin_amdgcn_s_barrier();
  int cur = 0;
  for (int kt = 0; kt < NIT; ++kt) {
    if (kt + 1 < NIT) { LOADB((kt + 1) * 32); STAGEA(cur ^ 1, (kt + 1) * 32); }
    const u16* S = &smem[cur][0];
#pragma unroll
    for (int n = 0; n < 4; ++n) {
      s16x8 bf = *(const s16x8*)(S + rb + n * 512);
#pragma unroll
      for (int m = 0; m < 8; ++m) {
        s16x8 af = *(const s16x8*)(S + ra + m * 512);
        acc[m][n] = __builtin_amdgcn_mfma_f32_16x16x32_bf16(af, bf, acc[m][n], 0, 0, 0);
      }
    }
    if (kt + 1 < NIT) {
      asm volatile("s_waitcnt vmcnt(0)" ::: "memory");
      __builtin_amdgcn_sched_barrier(0);
      WRITEB(cur ^ 1);
      asm volatile("s_waitcnt lgkmcnt(0)" ::: "memory");
      __builtin_amdgcn_sched_barrier(0);
      __builtin_amdgcn_s_barrier();
    }
    cur ^= 1;
  }

#pragma unroll
  for (int n = 0; n < 4; ++n) {
    const int col = nt * 256 + wc * 64 + n * 16 + (l & 15);
    const float bpv = (sk == 0) ? bp[(size_t)e * DIM + col] : 0.f;
#pragma unroll
    for (int m = 0; m < 8; ++m) {
#pragma unroll
      for (int r = 0; r < 4; ++r) {
        const int row = mt * 256 + wr * 128 + m * 16 + (l >> 4) * 4 + r;
        if (row < cnt) {
          const int idx = pfx + row;
          yp[((size_t)sk * (TOK * 2) + idx) * DIM + col] = entw[idx] * (acc[m][n][r] + bpv);
        }
      }
    }
  }
}

// ---------------- final: out[t] = sum over 2 slots x KSPLIT partials ----------------
__global__ __launch_bounds__(256) void k_final(const float* __restrict__ yp,
    const int* __restrict__ inv, float* __restrict__ out) {
  const int t = blockIdx.x;
  const int d = threadIdx.x * 4;
  const int i0 = inv[t * 2], i1 = inv[t * 2 + 1];
  float4 s = {0.f, 0.f, 0.f, 0.f};
#pragma unroll
  for (int sk = 0; sk < KSPLIT; ++sk) {
    float4 a = *(const float4*)(yp + ((size_t)sk * (TOK * 2) + i0) * DIM + d);
    float4 b = *(const float4*)(yp + ((size_t)sk * (TOK * 2) + i1) * DIM + d);
    s.x += a.x + b.x; s.y += a.y + b.y; s.z += a.z + b.z; s.w += a.w + b.w;
  }
  *(float4*)(out + (size_t)t * DIM + d) = s;
}

extern "C" void kernel_launch(void* const* d_in, const int* in_sizes, int n_in,
                              void* d_out, int out_size, void* d_ws, size_t ws_size,
                              hipStream_t stream) {
  const float* x      = (const float*)d_in[0];
  const float* noise  = (const float*)d_in[1];
  const float* gate_w = (const float*)d_in[2];
  const float* nw     = (const float*)d_in[3];
  const float* w1     = (const float*)d_in[4];
  const float* b1     = (const float*)d_in[5];
  const float* w2     = (const float*)d_in[6];
  const float* b2     = (const float*)d_in[7];
  const float* wp     = (const float*)d_in[8];
  const float* bp     = (const float*)d_in[9];
  float* out = (float*)d_out;
  char* ws = (char*)d_ws;

  const size_t SZ_X16 = (size_t)TOK * DIM * 2;                 //  4.2 MB
  const size_t SZ_ACT = (size_t)TOK * 2 * HID * 2;             // 33.6 MB
  const size_t SZ_YP  = (size_t)KSPLIT * TOK * 2 * DIM * 4;    // 67.1 MB

  u16* x16  = (u16*)ws;
  u16* act  = (u16*)(ws + SZ_X16);
  float* yp = (float*)(ws + SZ_X16 + SZ_ACT);
  char* meta = ws + SZ_X16 + SZ_ACT + SZ_YP;
  int*   tok_e    = (int*)(meta);
  float* tok_w    = (float*)(meta + 16384);
  int*   ent      = (int*)(meta + 32768);
  float* entw     = (float*)(meta + 49152);
  int*   bhist    = (int*)(meta + 65536);
  float* bgw      = (float*)(meta + 81920);
  int*   blk_off  = (int*)(meta + 98304);
  int*   inv      = (int*)(meta + 114688);
  int*   counts   = (int*)(meta + 131072);
  int*   prefix   = (int*)(meta + 131072 + 64);
  int*   tile_tab = (int*)(meta + 131072 + 128);

  k_gate<<<TOK / 4, 256, 0, stream>>>(x, noise, gate_w, nw, tok_e, tok_w, bhist, bgw, x16);
  k_scan<<<1, 512, 0, stream>>>(bhist, bgw, blk_off, prefix, counts, tile_tab,
                                out + (size_t)TOK * DIM);
  k_build<<<TOK / 256, 256, 0, stream>>>(tok_e, tok_w, prefix, blk_off, ent, entw, inv);
  k_gemm1f<<<dim3(HID / 128, TMAX), 512, 0, stream>>>(x16, w1, w2, b1, b2, ent,
                                                      counts, prefix, tile_tab, act);
  k_gemm2f<<<dim3(DIM / 256, TMAX, KSPLIT), 512, 0, stream>>>(act, wp, bp, entw,
                                                              counts, prefix, tile_tab, yp);
  k_final<<<TOK, 256, 0, stream>>>(yp, inv, out);
}

// Round 11
// 330.364 us; speedup vs baseline: 1.2351x; 1.1098x over previous
//
#include <hip/hip_runtime.h>

#define TOK 2048
#define DIM 1024
#define HID 4096
#define NE 8
#define KSPLIT 4
#define TMAX 24

typedef unsigned short u16;
typedef __attribute__((ext_vector_type(8))) short s16x8;
typedef __attribute__((ext_vector_type(4))) float f32x4;

__device__ __forceinline__ u16 f2b(float f) {
  unsigned u = __builtin_bit_cast(unsigned, f);
  unsigned r = (u + 0x7fffu + ((u >> 16) & 1u)) >> 16;
  return (u16)r;
}

__device__ __forceinline__ void gld_lds16(const void* g, void* l) {
  __builtin_amdgcn_global_load_lds((const __attribute__((address_space(1))) void*)g,
                                   (__attribute__((address_space(3))) void*)l, 16, 0, 0);
}

// ---------------- gating: one wave per token (512 blocks) ----------------
__global__ __launch_bounds__(256) void k_gate(const float* __restrict__ x,
    const float* __restrict__ noise, const float* __restrict__ gw,
    const float* __restrict__ nw,
    int* __restrict__ tok_e, float* __restrict__ tok_w,
    int* __restrict__ bhist, float* __restrict__ bgw, u16* __restrict__ x16) {
  const int wid = threadIdx.x >> 6, lane = threadIdx.x & 63;
  const int t = blockIdx.x * 4 + wid;
  const float* xr = x + (size_t)t * DIM + lane * 16;
  float acc[NE];
#pragma unroll
  for (int e = 0; e < NE; ++e) acc[e] = 0.f;
  u16 xb[16];
#pragma unroll
  for (int j = 0; j < 4; ++j) {
    float4 xv = *(const float4*)(xr + j * 4);
    xb[j * 4 + 0] = f2b(xv.x); xb[j * 4 + 1] = f2b(xv.y);
    xb[j * 4 + 2] = f2b(xv.z); xb[j * 4 + 3] = f2b(xv.w);
#pragma unroll
    for (int e = 0; e < NE; ++e) {
      float4 gv = *(const float4*)(gw + e * DIM + lane * 16 + j * 4);
      acc[e] += xv.x * gv.x + xv.y * gv.y + xv.z * gv.z + xv.w * gv.w;
    }
  }
  *(s16x8*)(x16 + (size_t)t * DIM + lane * 16) = *(const s16x8*)xb;
  *(s16x8*)(x16 + (size_t)t * DIM + lane * 16 + 8) = *(const s16x8*)(xb + 8);
#pragma unroll
  for (int e = 0; e < NE; ++e) {
#pragma unroll
    for (int off = 32; off >= 1; off >>= 1) acc[e] += __shfl_xor(acc[e], off);
  }
  float m = acc[0];
#pragma unroll
  for (int e = 1; e < NE; ++e) m = fmaxf(m, acc[e]);
  float p[NE]; float s = 0.f;
#pragma unroll
  for (int e = 0; e < NE; ++e) { p[e] = expf(acc[e] - m); s += p[e]; }
  float inv = 1.f / s;
  float v[NE];
#pragma unroll
  for (int e = 0; e < NE; ++e) v[e] = acc[e] + noise[t * NE + e] * nw[e];
  float v0 = -3.4e38f, v1 = -3.4e38f; int i0 = 0, i1 = 0;
#pragma unroll
  for (int e = 0; e < NE; ++e) {
    float ve = v[e];
    if (ve > v0) { v1 = v0; i1 = i0; v0 = ve; i0 = e; }
    else if (ve > v1) { v1 = ve; i1 = e; }
  }
  float e1 = expf(v1 - v0);
  float den = 1.f + e1;
  float w0 = 1.f / den, w1v = e1 / den;

  __shared__ float pl[4][NE];
  __shared__ int el[4][2];
  if (lane == 0) {
#pragma unroll
    for (int e = 0; e < NE; ++e) pl[wid][e] = p[e] * inv;
    el[wid][0] = i0; el[wid][1] = i1;
    tok_e[t * 2] = i0; tok_e[t * 2 + 1] = i1;
    tok_w[t * 2] = w0; tok_w[t * 2 + 1] = w1v;
  }
  __syncthreads();
  if (threadIdx.x < NE) {
    const int e = threadIdx.x;
    float ps = pl[0][e] + pl[1][e] + pl[2][e] + pl[3][e];
    int h = 0;
#pragma unroll
    for (int j = 0; j < 4; ++j) {
      h += (el[j][0] == e);
      h += (el[j][1] == e);
    }
    bgw[blockIdx.x * NE + e] = ps;
    bhist[blockIdx.x * NE + e] = h;
  }
}

// ---------------- scan: offsets, counts, prefix, 256-row tile table, lb loss ----------------
__global__ __launch_bounds__(512) void k_scan(const int* __restrict__ bhist,
    const float* __restrict__ bgw, int* __restrict__ blk_off, int* __restrict__ prefix,
    int* __restrict__ counts, int* __restrict__ tile_tab, float* __restrict__ loss_out) {
  const int i = threadIdx.x, lane = i & 63, wv = i >> 6;
  __shared__ int wsum[8];
  __shared__ float wfs[8];
  __shared__ int etot[8];
  __shared__ float fsum[8];
  for (int e = 0; e < NE; ++e) {
    int v = bhist[i * NE + e];
    int sc = v;
#pragma unroll
    for (int off = 1; off < 64; off <<= 1) {
      int u = __shfl_up(sc, off);
      if (lane >= off) sc += u;
    }
    float f = bgw[i * NE + e];
#pragma unroll
    for (int off = 32; off >= 1; off >>= 1) f += __shfl_xor(f, off);
    if (lane == 63) wsum[wv] = sc;
    if (lane == 0) wfs[wv] = f;
    __syncthreads();
    int base = 0;
    for (int w2 = 0; w2 < wv; ++w2) base += wsum[w2];
    blk_off[i * NE + e] = base + sc - v;
    if (i == 0) {
      float tf = 0.f;
      for (int w2 = 0; w2 < 8; ++w2) tf += wfs[w2];
      fsum[e] = tf;
    }
    if (i == 511) etot[e] = base + sc;
    __syncthreads();
  }
  if (i == 0) {
    int sacc = 0;
    float l = 0.f;
    int tt = 0;
#pragma unroll
    for (int e = 0; e < NE; ++e) { prefix[e] = sacc; counts[e] = etot[e]; sacc += etot[e]; }
    for (int e = 0; e < NE; ++e) {
      const int nmt = (etot[e] + 255) >> 8;
      for (int m2 = 0; m2 < nmt; ++m2) tile_tab[tt++] = (e << 16) | m2;
    }
    for (; tt < TMAX; ++tt) tile_tab[tt] = -1;
#pragma unroll
    for (int e = 0; e < NE; ++e) {
      float d = fsum[e] * (1.f / TOK) - 0.125f;
      l += d * d;
    }
    *loss_out = l * (0.01f / NE);
  }
}

// ---------------- build compacted expert lists + inverse map ----------------
__global__ __launch_bounds__(256) void k_build(const int* __restrict__ tok_e,
    const float* __restrict__ tok_w, const int* __restrict__ prefix,
    const int* __restrict__ blk_off, int* __restrict__ ent, float* __restrict__ entw,
    int* __restrict__ inv) {
  const int t = blockIdx.x * 256 + threadIdx.x;
  const int g = t >> 2;
  const int base = (t & 3) * 2;
  int ee[8];
#pragma unroll
  for (int j = 0; j < 8; ++j) ee[j] = tok_e[g * 8 + j];
#pragma unroll
  for (int s = 0; s < 2; ++s) {
    const int e = ee[base + s];
    int rank = 0;
#pragma unroll
    for (int j = 0; j < 8; ++j) rank += (j < base + s) && (ee[j] == e);
    const int idx = prefix[e] + blk_off[g * NE + e] + rank;
    ent[idx] = t * 2 + s;
    entw[idx] = tok_w[t * 2 + s];
    inv[t * 2 + s] = idx;
  }
}

// ====== GEMM1: 256x128 tile, 8 waves, fp32 B inline-cast, depth-2 B-reg pipeline ======
__global__ __launch_bounds__(512) void k_gemm1f(const u16* __restrict__ x16,
    const float* __restrict__ w1, const float* __restrict__ w2,
    const float* __restrict__ b1, const float* __restrict__ b2,
    const int* __restrict__ ent, const int* __restrict__ counts,
    const int* __restrict__ prefix, const int* __restrict__ tile_tab,
    u16* __restrict__ act) {
  const int tt = tile_tab[blockIdx.y];
  if (tt < 0) return;
  const int e = tt >> 16, mt = tt & 0xffff, nt = blockIdx.x;
  const int cnt = counts[e];
  const int pfx = prefix[e];
  const int tid = threadIdx.x, w = tid >> 6, l = tid & 63;

  __shared__ u16 smem[2][16384];   // A: [0,8192), B1: [8192,12288), B2: [12288,16384)

  const int r0 = tid >> 2;
  const int c = (tid & 3) ^ ((tid >> 3) & 3);
  int g0 = mt * 256 + r0;       if (g0 >= cnt) g0 = cnt - 1;
  int g1 = mt * 256 + 128 + r0; if (g1 >= cnt) g1 = cnt - 1;
  const u16* sa0 = x16 + (size_t)(ent[pfx + g0] >> 1) * DIM + c * 8;
  const u16* sa1 = x16 + (size_t)(ent[pfx + g1] >> 1) * DIM + c * 8;
  const float* pB1 = w1 + ((size_t)e * HID + nt * 128 + r0) * DIM + c * 8;
  const float* pB2 = w2 + ((size_t)e * HID + nt * 128 + r0) * DIM + c * 8;
  const int oA0 = tid * 8, oA1 = 4096 + tid * 8;
  const int oB1 = 8192 + tid * 8, oB2 = 12288 + tid * 8;

  const int wr = w >> 1, wc = w & 1;
  const int xs = ((l >> 4) ^ ((l >> 1) & 3)) * 8;
  const int ra = (wr * 64 + (l & 15)) * 32 + xs;
  const int rb = (wc * 64 + (l & 15)) * 32 + xs;

  f32x4 acc1[4][4], acc2[4][4];
#pragma unroll
  for (int m = 0; m < 4; ++m)
#pragma unroll
    for (int n = 0; n < 4; ++n) {
      acc1[m][n] = (f32x4){0.f, 0.f, 0.f, 0.f};
      acc2[m][n] = (f32x4){0.f, 0.f, 0.f, 0.f};
    }

  f32x4 a0_, a1_, a2_, a3_;   // B-reg set A
  f32x4 b0_, b1_, b2_, b3_;   // B-reg set B

  auto LOADB = [&](f32x4& r0_, f32x4& r1_, f32x4& r2_, f32x4& r3_, int k0) {
    r0_ = *(const f32x4*)(pB1 + k0);
    r1_ = *(const f32x4*)(pB1 + k0 + 4);
    r2_ = *(const f32x4*)(pB2 + k0);
    r3_ = *(const f32x4*)(pB2 + k0 + 4);
  };
  auto STAGEA = [&](int buf, int k0) {
    gld_lds16(sa0 + k0, &smem[buf][oA0]);
    gld_lds16(sa1 + k0, &smem[buf][oA1]);
  };
  auto WRITEB = [&](int buf, const f32x4& r0_, const f32x4& r1_,
                    const f32x4& r2_, const f32x4& r3_) {
    u16 u[16];
    u[0] = f2b(r0_[0]); u[1] = f2b(r0_[1]); u[2] = f2b(r0_[2]); u[3] = f2b(r0_[3]);
    u[4] = f2b(r1_[0]); u[5] = f2b(r1_[1]); u[6] = f2b(r1_[2]); u[7] = f2b(r1_[3]);
    u[8] = f2b(r2_[0]); u[9] = f2b(r2_[1]); u[10] = f2b(r2_[2]); u[11] = f2b(r2_[3]);
    u[12] = f2b(r3_[0]); u[13] = f2b(r3_[1]); u[14] = f2b(r3_[2]); u[15] = f2b(r3_[3]);
    *(s16x8*)&smem[buf][oB1] = *(const s16x8*)u;
    *(s16x8*)&smem[buf][oB2] = *(const s16x8*)(u + 8);
  };
  auto MSTEP = [&](int cur) {
    const u16* S = &smem[cur][0];
    s16x8 af[4];
#pragma unroll
    for (int m = 0; m < 4; ++m) af[m] = *(const s16x8*)(S + ra + m * 512);
#pragma unroll
    for (int n = 0; n < 4; ++n) {
      s16x8 bf1 = *(const s16x8*)(S + 8192 + rb + n * 512);
      s16x8 bf2 = *(const s16x8*)(S + 12288 + rb + n * 512);
#pragma unroll
      for (int m = 0; m < 4; ++m) {
        acc1[m][n] = __builtin_amdgcn_mfma_f32_16x16x32_bf16(af[m], bf1, acc1[m][n], 0, 0, 0);
        acc2[m][n] = __builtin_amdgcn_mfma_f32_16x16x32_bf16(af[m], bf2, acc2[m][n], 0, 0, 0);
      }
    }
  };

  const int NT = DIM / 32;   // 32, even
  // prologue: invariant after = buf0 complete; outstanding = LOADB(1)[4] + STAGEA(1)[2]
  LOADB(a0_, a1_, a2_, a3_, 0);
  STAGEA(0, 0);
  LOADB(b0_, b1_, b2_, b3_, 32);
  asm volatile("s_waitcnt vmcnt(4)" ::: "memory");
  __builtin_amdgcn_sched_barrier(0);
  WRITEB(0, a0_, a1_, a2_, a3_);
  STAGEA(1, 32);
  asm volatile("s_waitcnt lgkmcnt(0)" ::: "memory");
  __builtin_amdgcn_sched_barrier(0);
  __builtin_amdgcn_s_barrier();

  for (int kt = 0; kt < NT; kt += 2) {
    // ---- even iter kt: consume buf0; finalize tile kt+1 into buf1 ----
    if (kt + 2 < NT) LOADB(a0_, a1_, a2_, a3_, (kt + 2) * 32);
    MSTEP(0);
    __builtin_amdgcn_s_barrier();               // all waves done reading buf0
    if (kt + 2 < NT) asm volatile("s_waitcnt vmcnt(4)" ::: "memory");
    else             asm volatile("s_waitcnt vmcnt(0)" ::: "memory");
    __builtin_amdgcn_sched_barrier(0);
    WRITEB(1, b0_, b1_, b2_, b3_);
    if (kt + 2 < NT) STAGEA(0, (kt + 2) * 32);
    asm volatile("s_waitcnt lgkmcnt(0)" ::: "memory");
    __builtin_amdgcn_sched_barrier(0);
    __builtin_amdgcn_s_barrier();
    // ---- odd iter kt+1: consume buf1; finalize tile kt+2 into buf0 ----
    if (kt + 3 < NT) LOADB(b0_, b1_, b2_, b3_, (kt + 3) * 32);
    MSTEP(1);
    if (kt + 2 < NT) {
      __builtin_amdgcn_s_barrier();
      if (kt + 3 < NT) asm volatile("s_waitcnt vmcnt(4)" ::: "memory");
      else             asm volatile("s_waitcnt vmcnt(0)" ::: "memory");
      __builtin_amdgcn_sched_barrier(0);
      WRITEB(0, a0_, a1_, a2_, a3_);
      if (kt + 3 < NT) STAGEA(1, (kt + 3) * 32);
      asm volatile("s_waitcnt lgkmcnt(0)" ::: "memory");
      __builtin_amdgcn_sched_barrier(0);
      __builtin_amdgcn_s_barrier();
    }
  }

#pragma unroll
  for (int n = 0; n < 4; ++n) {
    const int col = nt * 128 + wc * 64 + n * 16 + (l & 15);
    const float bb1 = b1[(size_t)e * HID + col];
    const float bb2 = b2[(size_t)e * HID + col];
#pragma unroll
    for (int m = 0; m < 4; ++m) {
#pragma unroll
      for (int r = 0; r < 4; ++r) {
        const int row = mt * 256 + wr * 64 + m * 16 + (l >> 4) * 4 + r;
        if (row < cnt) {
          float h = acc1[m][n][r] + bb1;
          float g = acc2[m][n][r] + bb2;
          float a = h * g / (1.f + expf(-g));
          act[(size_t)(pfx + row) * HID + col] = f2b(a);
        }
      }
    }
  }
}

// ====== GEMM2: 256x256 tile, 8 waves, split-K=4, fp32 wp inline-cast, depth-2 pipeline ======
__global__ __launch_bounds__(512) void k_gemm2f(const u16* __restrict__ act,
    const float* __restrict__ wp, const float* __restrict__ bp,
    const float* __restrict__ entw, const int* __restrict__ counts,
    const int* __restrict__ prefix, const int* __restrict__ tile_tab,
    float* __restrict__ yp) {
  const int tt = tile_tab[blockIdx.y];
  if (tt < 0) return;
  const int e = tt >> 16, mt = tt & 0xffff;
  const int sk = blockIdx.z, nt = blockIdx.x;
  const int cnt = counts[e];
  const int pfx = prefix[e];
  const int tid = threadIdx.x, w = tid >> 6, l = tid & 63;

  __shared__ u16 smem[2][16384];   // A: [0,8192), B: [8192,16384)

  const int r0 = tid >> 2;
  const int c = (tid & 3) ^ ((tid >> 3) & 3);
  int g0 = mt * 256 + r0;       if (g0 >= cnt) g0 = cnt - 1;
  int g1 = mt * 256 + 128 + r0; if (g1 >= cnt) g1 = cnt - 1;
  const int kbase = sk * (HID / KSPLIT);
  const u16* sa0 = act + (size_t)(pfx + g0) * HID + kbase + c * 8;
  const u16* sa1 = act + (size_t)(pfx + g1) * HID + kbase + c * 8;
  const float* pB0 = wp + ((size_t)e * DIM + nt * 256 + r0) * HID + kbase + c * 8;
  const float* pB1h = pB0 + (size_t)128 * HID;
  const int oA0 = tid * 8, oA1 = 4096 + tid * 8;
  const int oB0 = 8192 + tid * 8, oB1 = 12288 + tid * 8;

  const int wr = w >> 2, wc = w & 3;
  const int xs = ((l >> 4) ^ ((l >> 1) & 3)) * 8;
  const int ra = (wr * 128 + (l & 15)) * 32 + xs;
  const int rb = 8192 + (wc * 64 + (l & 15)) * 32 + xs;

  f32x4 acc[8][4];
#pragma unroll
  for (int m = 0; m < 8; ++m)
#pragma unroll
    for (int n = 0; n < 4; ++n) acc[m][n] = (f32x4){0.f, 0.f, 0.f, 0.f};

  f32x4 a0_, a1_, a2_, a3_;
  f32x4 b0_, b1_, b2_, b3_;

  auto LOADB = [&](f32x4& r0_, f32x4& r1_, f32x4& r2_, f32x4& r3_, int k0) {
    r0_ = *(const f32x4*)(pB0 + k0);
    r1_ = *(const f32x4*)(pB0 + k0 + 4);
    r2_ = *(const f32x4*)(pB1h + k0);
    r3_ = *(const f32x4*)(pB1h + k0 + 4);
  };
  auto STAGEA = [&](int buf, int k0) {
    gld_lds16(sa0 + k0, &smem[buf][oA0]);
    gld_lds16(sa1 + k0, &smem[buf][oA1]);
  };
  auto WRITEB = [&](int buf, const f32x4& r0_, const f32x4& r1_,
                    const f32x4& r2_, const f32x4& r3_) {
    u16 u[16];
    u[0] = f2b(r0_[0]); u[1] = f2b(r0_[1]); u[2] = f2b(r0_[2]); u[3] = f2b(r0_[3]);
    u[4] = f2b(r1_[0]); u[5] = f2b(r1_[1]); u[6] = f2b(r1_[2]); u[7] = f2b(r1_[3]);
    u[8] = f2b(r2_[0]); u[9] = f2b(r2_[1]); u[10] = f2b(r2_[2]); u[11] = f2b(r2_[3]);
    u[12] = f2b(r3_[0]); u[13] = f2b(r3_[1]); u[14] = f2b(r3_[2]); u[15] = f2b(r3_[3]);
    *(s16x8*)&smem[buf][oB0] = *(const s16x8*)u;
    *(s16x8*)&smem[buf][oB1] = *(const s16x8*)(u + 8);
  };
  auto MSTEP = [&](int cur) {
    const u16* S = &smem[cur][0];
#pragma unroll
    for (int n = 0; n < 4; ++n) {
      s16x8 bf = *(const s16x8*)(S + rb + n * 512);
#pragma unroll
      for (int m = 0; m < 8; ++m) {
        s16x8 af = *(const s16x8*)(S + ra + m * 512);
        acc[m][n] = __builtin_amdgcn_mfma_f32_16x16x32_bf16(af, bf, acc[m][n], 0, 0, 0);
      }
    }
  };

  const int NIT = HID / KSPLIT / 32;   // 32, even
  LOADB(a0_, a1_, a2_, a3_, 0);
  STAGEA(0, 0);
  LOADB(b0_, b1_, b2_, b3_, 32);
  asm volatile("s_waitcnt vmcnt(4)" ::: "memory");
  __builtin_amdgcn_sched_barrier(0);
  WRITEB(0, a0_, a1_, a2_, a3_);
  STAGEA(1, 32);
  asm volatile("s_waitcnt lgkmcnt(0)" ::: "memory");
  __builtin_amdgcn_sched_barrier(0);
  __builtin_amdgcn_s_barrier();

  for (int kt = 0; kt < NIT; kt += 2) {
    if (kt + 2 < NIT) LOADB(a0_, a1_, a2_, a3_, (kt + 2) * 32);
    MSTEP(0);
    __builtin_amdgcn_s_barrier();
    if (kt + 2 < NIT) asm volatile("s_waitcnt vmcnt(4)" ::: "memory");
    else              asm volatile("s_waitcnt vmcnt(0)" ::: "memory");
    __builtin_amdgcn_sched_barrier(0);
    WRITEB(1, b0_, b1_, b2_, b3_);
    if (kt + 2 < NIT) STAGEA(0, (kt + 2) * 32);
    asm volatile("s_waitcnt lgkmcnt(0)" ::: "memory");
    __builtin_amdgcn_sched_barrier(0);
    __builtin_amdgcn_s_barrier();
    if (kt + 3 < NIT) LOADB(b0_, b1_, b2_, b3_, (kt + 3) * 32);
    MSTEP(1);
    if (kt + 2 < NIT) {
      __builtin_amdgcn_s_barrier();
      if (kt + 3 < NIT) asm volatile("s_waitcnt vmcnt(4)" ::: "memory");
      else              asm volatile("s_waitcnt vmcnt(0)" ::: "memory");
      __builtin_amdgcn_sched_barrier(0);
      WRITEB(0, a0_, a1_, a2_, a3_);
      if (kt + 3 < NIT) STAGEA(1, (kt + 3) * 32);
      asm volatile("s_waitcnt lgkmcnt(0)" ::: "memory");
      __builtin_amdgcn_sched_barrier(0);
      __builtin_amdgcn_s_barrier();
    }
  }

#pragma unroll
  for (int n = 0; n < 4; ++n) {
    const int col = nt * 256 + wc * 64 + n * 16 + (l & 15);
    const float bpv = (sk == 0) ? bp[(size_t)e * DIM + col] : 0.f;
#pragma unroll
    for (int m = 0; m < 8; ++m) {
#pragma unroll
      for (int r = 0; r < 4; ++r) {
        const int row = mt * 256 + wr * 128 + m * 16 + (l >> 4) * 4 + r;
        if (row < cnt) {
          const int idx = pfx + row;
          yp[((size_t)sk * (TOK * 2) + idx) * DIM + col] = entw[idx] * (acc[m][n][r] + bpv);
        }
      }
    }
  }
}

// ---------------- final: out[t] = sum over 2 slots x KSPLIT partials ----------------
__global__ __launch_bounds__(256) void k_final(const float* __restrict__ yp,
    const int* __restrict__ inv, float* __restrict__ out) {
  const int t = blockIdx.x;
  const int d = threadIdx.x * 4;
  const int i0 = inv[t * 2], i1 = inv[t * 2 + 1];
  float4 s = {0.f, 0.f, 0.f, 0.f};
#pragma unroll
  for (int sk = 0; sk < KSPLIT; ++sk) {
    float4 a = *(const float4*)(yp + ((size_t)sk * (TOK * 2) + i0) * DIM + d);
    float4 b = *(const float4*)(yp + ((size_t)sk * (TOK * 2) + i1) * DIM + d);
    s.x += a.x + b.x; s.y += a.y + b.y; s.z += a.z + b.z; s.w += a.w + b.w;
  }
  *(float4*)(out + (size_t)t * DIM + d) = s;
}

extern "C" void kernel_launch(void* const* d_in, const int* in_sizes, int n_in,
                              void* d_out, int out_size, void* d_ws, size_t ws_size,
                              hipStream_t stream) {
  const float* x      = (const float*)d_in[0];
  const float* noise  = (const float*)d_in[1];
  const float* gate_w = (const float*)d_in[2];
  const float* nw     = (const float*)d_in[3];
  const float* w1     = (const float*)d_in[4];
  const float* b1     = (const float*)d_in[5];
  const float* w2     = (const float*)d_in[6];
  const float* b2     = (const float*)d_in[7];
  const float* wp     = (const float*)d_in[8];
  const float* bp     = (const float*)d_in[9];
  float* out = (float*)d_out;
  char* ws = (char*)d_ws;

  const size_t SZ_X16 = (size_t)TOK * DIM * 2;
  const size_t SZ_ACT = (size_t)TOK * 2 * HID * 2;
  const size_t SZ_YP  = (size_t)KSPLIT * TOK * 2 * DIM * 4;

  u16* x16  = (u16*)ws;
  u16* act  = (u16*)(ws + SZ_X16);
  float* yp = (float*)(ws + SZ_X16 + SZ_ACT);
  char* meta = ws + SZ_X16 + SZ_ACT + SZ_YP;
  int*   tok_e    = (int*)(meta);
  float* tok_w    = (float*)(meta + 16384);
  int*   ent      = (int*)(meta + 32768);
  float* entw     = (float*)(meta + 49152);
  int*   bhist    = (int*)(meta + 65536);
  float* bgw      = (float*)(meta + 81920);
  int*   blk_off  = (int*)(meta + 98304);
  int*   inv      = (int*)(meta + 114688);
  int*   counts   = (int*)(meta + 131072);
  int*   prefix   = (int*)(meta + 131072 + 64);
  int*   tile_tab = (int*)(meta + 131072 + 128);

  k_gate<<<TOK / 4, 256, 0, stream>>>(x, noise, gate_w, nw, tok_e, tok_w, bhist, bgw, x16);
  k_scan<<<1, 512, 0, stream>>>(bhist, bgw, blk_off, prefix, counts, tile_tab,
                                out + (size_t)TOK * DIM);
  k_build<<<TOK / 256, 256, 0, stream>>>(tok_e, tok_w, prefix, blk_off, ent, entw, inv);
  k_gemm1f<<<dim3(HID / 128, TMAX), 512, 0, stream>>>(x16, w1, w2, b1, b2, ent,
                                                      counts, prefix, tile_tab, act);
  k_gemm2f<<<dim3(DIM / 256, TMAX, KSPLIT), 512, 0, stream>>>(act, wp, bp, entw,
                                                              counts, prefix, tile_tab, yp);
  k_final<<<TOK, 256, 0, stream>>>(yp, inv, out);
}